// Round 4
// baseline (241.717 us; speedup 1.0000x reference)
//
#include <hip/hip_runtime.h>

// Bidirectional GRU (H=32, input=1, B=2048, T=512) + MLP head, fully fused.
//
// Reference takes out[:, -1, :] = concat(h_fwd after T steps, h_bwd after ONE
// step from h0=0 on x[T-1]) -> only the forward scan is sequential; W_hh_b is
// entirely unused.
//
// R15 = R11's wave (proven cheapest per-row issue: 340 cyc/step for 2 rows)
// with ONLY the launch geometry changed to get 2 waves/SIMD.
//
// Model (R8..R14): R11 wall 532 cyc/step = 340 issue + ~190 stall at 1
// wave/SIMD; the stall (h LDS round-trip + trans tail) is unhidable with one
// wave. R12 (DPP butterfly) and R13/R14 (K-split + permlane combines) both
// ADDED more issue than stall they hid -- per-row issue must not grow.
// R15: keep the R11 wave byte-for-byte; launch 128 blocks x 512 threads
// (8 waves/block, 16 rows/block). One block per CU -> 8 waves on 4 SIMDs =
// exactly 2 independent R11-waves per SIMD (guaranteed by block geometry, no
// placement assumptions). No cross-wave barriers: waves free-run, each wave's
// ~190-cyc stall hides under the other's 340-cyc issue.
// Per SIMD: 680 issue / 4 rows = 170 cyc/row vs R11's 266. The other 128 CUs
// idle -- irrelevant for a latency-bound serial scan.
//
// Wave structure (unchanged from R11):
//   * 32 lanes per row, full 32-wide f16 dot2 per lane, no shfl; 2 rows per
//     wave as half-waves.
//   * Weights f16 packed (16 h2 per gate = 48 VGPRs), pre-scaled into exp2
//     domain (r/z by -log2e, n by 2log2e), pinned via inline-asm "+v".
//   * h state fp32 per lane; broadcast copy f16 via ds_write_b16 + 4x
//     broadcast ds_read_b128 (conflict-free; latency now hidden by TLP).
//   * sigmoid = v_rcp(1+v_exp2(.)), tanh = 1-2*v_rcp(1+v_exp2(.)).
//   * x staged in LDS f32, consumed as vf4 per 4 steps (prefetched);
//     x-term FMAs for all 4 unrolled steps hoisted to the tg-loop top.

typedef float vf2 __attribute__((ext_vector_type(2)));
typedef float vf4 __attribute__((ext_vector_type(4)));
typedef _Float16 f16;
typedef f16 h2 __attribute__((ext_vector_type(2)));
typedef f16 h8 __attribute__((ext_vector_type(8)));

#define TT 512
#define HH 32
#define RPB 16   // rows per block (16 row-groups = 8 waves = 2 per SIMD)

// inline-asm defs are not rematerializable: forces a real VGPR def here.
#define PIN(v) asm volatile("" : "+v"(v))

#define LOG2E 1.44269504f

__device__ __forceinline__ float fast_sigm(float a) {   // sigmoid(a)
  return __builtin_amdgcn_rcpf(1.0f + __builtin_amdgcn_exp2f(-LOG2E * a));
}
__device__ __forceinline__ float fast_tanh(float a) {   // tanh(a)
  return __builtin_fmaf(-2.0f,
      __builtin_amdgcn_rcpf(1.0f + __builtin_amdgcn_exp2f(2.0f * LOG2E * a)),
      1.0f);
}

__device__ __forceinline__ h2 pack_h2(vf2 a, float s) {
  h2 r = {(f16)(a.x * s), (f16)(a.y * s)};
  return r;
}

// load one 32-float W_hh row as 16 packed-f16 h2 regs, pre-scaled, pinned
#define LDW16(P, BASE, S) \
  h2 P##0=pack_h2(Wp[(BASE)+0],(S)),  P##1=pack_h2(Wp[(BASE)+1],(S)), \
     P##2=pack_h2(Wp[(BASE)+2],(S)),  P##3=pack_h2(Wp[(BASE)+3],(S)), \
     P##4=pack_h2(Wp[(BASE)+4],(S)),  P##5=pack_h2(Wp[(BASE)+5],(S)), \
     P##6=pack_h2(Wp[(BASE)+6],(S)),  P##7=pack_h2(Wp[(BASE)+7],(S)), \
     P##8=pack_h2(Wp[(BASE)+8],(S)),  P##9=pack_h2(Wp[(BASE)+9],(S)), \
     P##A=pack_h2(Wp[(BASE)+10],(S)), P##B=pack_h2(Wp[(BASE)+11],(S)), \
     P##C=pack_h2(Wp[(BASE)+12],(S)), P##D=pack_h2(Wp[(BASE)+13],(S)), \
     P##E=pack_h2(Wp[(BASE)+14],(S)), P##F=pack_h2(Wp[(BASE)+15],(S)); \
  PIN(P##0);PIN(P##1);PIN(P##2);PIN(P##3);PIN(P##4);PIN(P##5);PIN(P##6);PIN(P##7); \
  PIN(P##8);PIN(P##9);PIN(P##A);PIN(P##B);PIN(P##C);PIN(P##D);PIN(P##E);PIN(P##F)

// 16 v_dot2_f32_f16 of (q0..qF).(P0..PF) into two chains A0,A1; A0 seeded.
#define FDOT16(A0, A1, P, SEED) \
  float A0 = __builtin_amdgcn_fdot2(q0, P##0, (SEED), false); \
  float A1 = __builtin_amdgcn_fdot2(q1, P##1, 0.0f, false); \
  A0 = __builtin_amdgcn_fdot2(q2, P##2, A0, false);  A1 = __builtin_amdgcn_fdot2(q3, P##3, A1, false); \
  A0 = __builtin_amdgcn_fdot2(q4, P##4, A0, false);  A1 = __builtin_amdgcn_fdot2(q5, P##5, A1, false); \
  A0 = __builtin_amdgcn_fdot2(q6, P##6, A0, false);  A1 = __builtin_amdgcn_fdot2(q7, P##7, A1, false); \
  A0 = __builtin_amdgcn_fdot2(q8, P##8, A0, false);  A1 = __builtin_amdgcn_fdot2(q9, P##9, A1, false); \
  A0 = __builtin_amdgcn_fdot2(qA, P##A, A0, false);  A1 = __builtin_amdgcn_fdot2(qB, P##B, A1, false); \
  A0 = __builtin_amdgcn_fdot2(qC, P##C, A0, false);  A1 = __builtin_amdgcn_fdot2(qD, P##D, A1, false); \
  A0 = __builtin_amdgcn_fdot2(qE, P##E, A0, false);  A1 = __builtin_amdgcn_fdot2(qF, P##F, A1, false)

__global__ __launch_bounds__(512)
__attribute__((amdgpu_waves_per_eu(2, 2)))
void gru_bidir_head(const float* __restrict__ X,
                    const float* __restrict__ Wih_f, const float* __restrict__ Whh_f,
                    const float* __restrict__ bih_f, const float* __restrict__ bhh_f,
                    const float* __restrict__ Wih_b,
                    const float* __restrict__ bih_b, const float* __restrict__ bhh_b,
                    const float* __restrict__ W1, const float* __restrict__ b1,
                    const float* __restrict__ W2, const float* __restrict__ b2,
                    float* __restrict__ out)
{
  __shared__ float xbuf[RPB][TT];      // staged input rows (32 KB)
  __shared__ f16   hbuf[RPB][HH];      // h broadcast, f16 (1 KB)
  __shared__ float obuf[RPB][64];      // [row][h_f(32) | h_b(32)] (4 KB)

  const int g  = threadIdx.x & 31;     // lane within row group = output index i
  const int rs = threadIdx.x >> 5;     // row slot in block (0..15)
  const int b  = (blockIdx.x << 4) + rs;

  // --- stage this row of X into LDS (4 x vf4 per lane, coalesced) ---
  const vf4* Xr4 = (const vf4*)(X + (size_t)b * TT);
  vf4* xb4 = (vf4*)&xbuf[rs][0];
  #pragma unroll
  for (int q = 0; q < 4; ++q) xb4[g + 32 * q] = Xr4[g + 32 * q];

  // --- per-lane weights: W_hh rows g (r), 32+g (z), 64+g (n); pre-scaled
  //     into exp2 domain, packed f16, pinned (48 VGPRs) ---
  const vf2* Wp = (const vf2*)Whh_f;   // row stride = 16 vf2
  const float s1 = -LOG2E;             // r,z: sigmoid domain (negated)
  const float s2 = 2.0f * LOG2E;       // n: tanh domain
  LDW16(Wr, (g)        * 16, s1);
  LDW16(Wz, (HH + g)   * 16, s1);
  LDW16(Wn, (2*HH + g) * 16, s2);

  float xwr = Wih_f[g] * s1, xwz = Wih_f[HH + g] * s1, xwn = Wih_f[2*HH + g] * s2;
  float cbr = (bih_f[g]      + bhh_f[g])      * s1;
  float cbz = (bih_f[HH + g] + bhh_f[HH + g]) * s1;
  float cbn = bih_f[2*HH + g] * s2;            // n: b_ih term (with x)
  float cbh = bhh_f[2*HH + g] * s2;            // n: b_hh term (inside r*(...))
  PIN(xwr); PIN(xwz); PIN(xwn); PIN(cbr); PIN(cbz); PIN(cbn); PIN(cbh);

  float h = 0.0f;
  hbuf[rs][g] = (f16)0.0f;
  __builtin_amdgcn_wave_barrier();

  const h8*  hv = (const h8*)&hbuf[rs][0];     // 4 x b128 = all 32 f16 h
  const vf4* xv = (const vf4*)&xbuf[rs][0];
  vf4 x4 = xv[0];

  #pragma unroll 1
  for (int tg = 0; tg < TT / 4; ++tg) {
    const vf4 x4n = xv[tg + 1 < TT / 4 ? tg + 1 : tg];   // off critical path

    // hoist ALL x-dependent terms for the 4 sub-steps: issued during the
    // first read stall, off the per-step serial chain.
    float sr0 = __builtin_fmaf(x4.x, xwr, cbr), sz0 = __builtin_fmaf(x4.x, xwz, cbz),
          sn0 = __builtin_fmaf(x4.x, xwn, cbn);
    float sr1 = __builtin_fmaf(x4.y, xwr, cbr), sz1 = __builtin_fmaf(x4.y, xwz, cbz),
          sn1 = __builtin_fmaf(x4.y, xwn, cbn);
    float sr2 = __builtin_fmaf(x4.z, xwr, cbr), sz2 = __builtin_fmaf(x4.z, xwz, cbz),
          sn2 = __builtin_fmaf(x4.z, xwn, cbn);
    float sr3 = __builtin_fmaf(x4.w, xwr, cbr), sz3 = __builtin_fmaf(x4.w, xwz, cbz),
          sn3 = __builtin_fmaf(x4.w, xwn, cbn);

    #pragma unroll
    for (int u = 0; u < 4; ++u) {
      const float sr = (u == 0) ? sr0 : (u == 1) ? sr1 : (u == 2) ? sr2 : sr3;
      const float sz = (u == 0) ? sz0 : (u == 1) ? sz1 : (u == 2) ? sz2 : sz3;
      const float sn = (u == 0) ? sn0 : (u == 1) ? sn1 : (u == 2) ? sn2 : sn3;

      // all 32 h (f16): 4 broadcast ds_read_b128 (latency hidden by the
      // co-resident wave on this SIMD; no pins)
      const h8 H0 = hv[0], H1 = hv[1], H2 = hv[2], H3 = hv[3];
      const h2 q0 = {H0[0], H0[1]}, q1 = {H0[2], H0[3]}, q2 = {H0[4], H0[5]}, q3 = {H0[6], H0[7]},
               q4 = {H1[0], H1[1]}, q5 = {H1[2], H1[3]}, q6 = {H1[4], H1[5]}, q7 = {H1[6], H1[7]},
               q8 = {H2[0], H2[1]}, q9 = {H2[2], H2[3]}, qA = {H2[4], H2[5]}, qB = {H2[6], H2[7]},
               qC = {H3[0], H3[1]}, qD = {H3[2], H3[3]}, qE = {H3[4], H3[5]}, qF = {H3[6], H3[7]};

      FDOT16(Ra, Rb, Wr, sr);
      FDOT16(Za, Zb, Wz, sz);
      FDOT16(Na, Nb, Wn, cbh);

      const float ar = Ra + Rb;                  // includes x-term + bias
      const float az = Za + Zb;
      const float r = __builtin_amdgcn_rcpf(1.0f + __builtin_amdgcn_exp2f(ar));
      const float z = __builtin_amdgcn_rcpf(1.0f + __builtin_amdgcn_exp2f(az));
      const float y = __builtin_fmaf(r, Na + Nb, sn);
      const float n = __builtin_fmaf(-2.0f,
          __builtin_amdgcn_rcpf(1.0f + __builtin_amdgcn_exp2f(y)), 1.0f);
      h = __builtin_fmaf(z, h - n, n);           // (1-z)*n + z*h

      hbuf[rs][g] = (f16)h;                      // v_cvt + ds_write_b16
      __builtin_amdgcn_wave_barrier();           // wave-synchronous ordering
    }
    x4 = x4n;
  }

  // --- backward direction: exactly ONE GRU step from h0=0 on x[T-1] ---
  const float xl  = xbuf[rs][TT - 1];
  const float rb  = fast_sigm(__builtin_fmaf(xl, Wih_b[g],      bih_b[g]      + bhh_b[g]));
  const float zb  = fast_sigm(__builtin_fmaf(xl, Wih_b[HH + g], bih_b[HH + g] + bhh_b[HH + g]));
  const float xnb = __builtin_fmaf(xl, Wih_b[2*HH + g], bih_b[2*HH + g]);
  const float nb  = fast_tanh(__builtin_fmaf(rb, bhh_b[2*HH + g], xnb));
  const float hb  = nb - zb * nb;                // (1-zb)*nb + zb*0

  obuf[rs][g]      = h;                          // h_f (full fp32 state)
  obuf[rs][32 + g] = hb;                         // h_b
  __builtin_amdgcn_wave_barrier();

  // --- MLP head: sigmoid(W2 @ relu(W1 @ [h_f,h_b] + b1) + b2) ---
  const int j = g & 15;                          // lanes 16..31 duplicate
  const vf4* W1r = (const vf4*)(W1 + j * 64);
  const vf4* hc  = (const vf4*)&obuf[rs][0];
  vf4 a4 = W1r[0] * hc[0];
  #pragma unroll
  for (int q = 1; q < 16; ++q)
    a4 = __builtin_elementwise_fma(W1r[q], hc[q], a4);
  float acc = b1[j] + (a4.x + a4.y) + (a4.z + a4.w);
  float h1 = fmaxf(acc, 0.0f) * W2[j];
  h1 += __shfl_down(h1, 8, 16);
  h1 += __shfl_down(h1, 4, 16);
  h1 += __shfl_down(h1, 2, 16);
  h1 += __shfl_down(h1, 1, 16);
  if (g == 0) out[b] = fast_sigm(h1 + b2[0]);
}

extern "C" void kernel_launch(void* const* d_in, const int* in_sizes, int n_in,
                              void* d_out, int out_size, void* d_ws, size_t ws_size,
                              hipStream_t stream) {
  const float* X     = (const float*)d_in[0];
  const float* Wih_f = (const float*)d_in[1];
  const float* Whh_f = (const float*)d_in[2];
  const float* bih_f = (const float*)d_in[3];
  const float* bhh_f = (const float*)d_in[4];
  const float* Wih_b = (const float*)d_in[5];
  // d_in[6] = W_hh_b: unused — backward direction runs exactly one step from h0=0.
  const float* bih_b = (const float*)d_in[7];
  const float* bhh_b = (const float*)d_in[8];
  const float* W1    = (const float*)d_in[9];
  const float* b1    = (const float*)d_in[10];
  const float* W2    = (const float*)d_in[11];
  const float* b2    = (const float*)d_in[12];
  float* out = (float*)d_out;

  // 2048 rows / 16 rows per 512-thread block = 128 blocks. One block per CU:
  // 8 waves on 4 SIMDs = exactly 2 independent R11-style waves per SIMD, so
  // each wave's LDS/trans stall hides under the other wave's issue.
  gru_bidir_head<<<128, 512, 0, stream>>>(X, Wih_f, Whh_f, bih_f, bhh_f,
                                          Wih_b, bih_b, bhh_b, W1, b1, W2, b2, out);
}

// Round 5
// 219.780 us; speedup vs baseline: 1.0998x; 1.0998x over previous
//
#include <hip/hip_runtime.h>

// Bidirectional GRU (H=32, input=1, B=2048, T=512) + MLP head, fully fused.
//
// Reference takes out[:, -1, :] = concat(h_fwd after T steps, h_bwd after ONE
// step from h0=0 on x[T-1]) -> only the forward scan is sequential; W_hh_b is
// entirely unused.
//
// R16: recurrence matmul moved onto the matrix pipe (MFMA).
//
// R12-R15 post-mortems mapped the box: per-row VALU issue (~170 cyc/row,
// dominated by 24 v_dot2 instr/row) is the floor of the fdot2 family; wave
// geometry cannot change it (R13/R14 K-split: +issue; R15 2-wave/SIMD:
// per-row 210 but half the chip idle). MfmaUtil=0 all session: the pipe that
// does dot-products for free sat idle. R16: per step, gh = h @ W_hh.T is a
// [16x32]x[32x96] GEMM = 6 v_mfma_f32_16x16x32_f16 replacing 768 fdot2.
//
//   * 128 blocks x 128 thr; block = 16 batch rows, 2 waves split by gate-half
//     (wave W computes j in [16W, 16W+16) of r,z,n -> 3 MFMA each).
//   * K-labeling trick: MFMA is correct for ANY lane/elem->k labeling as long
//     as A and B agree. Choose k = 4q+(e&3)+16*(e>>2) (q=lane>>4). Then the
//     D-layout (n=lane&15 -> batch row b, m=4q+reg -> j, layout verified in
//     guide m89) aligns EXACTLY with the next step's B-fragment: h_new stays
//     in registers, zero cross-lane shuffles for the recurrence.
//   * Seeds ride the MFMA C operand: C_r/C_z = x[b]*Wih[j]*s + cb[j] (12 FMA
//     per step, off-chain); C_n = bhh_n consts (free). exp2-domain pre-scale
//     as before (r/z by -log2e, n by 2log2e) applied to A-frags and seeds.
//   * Cross-wave half-exchange: each wave ds_write_b64's its 4 f16 h-values
//     (own j's), __syncthreads(), both waves read both halves (2x b64).
//     Double-buffered by step parity -> race-free with one barrier/step.
//   * Epilogue per lane: 4 j's -> 24 trans + ~28 VALU; trans now dominate
//     (~96 of ~240 cyc/step/wave). h kept f32, quantized f16 for the dots
//     (identical to R11 numerics).
//   * Backward direction (one step from h0=0) + MLP head unchanged, run
//     per-row by 32-lane groups, 4 iterations.

typedef float vf2 __attribute__((ext_vector_type(2)));
typedef float vf4 __attribute__((ext_vector_type(4)));
typedef _Float16 f16;
typedef f16 h2 __attribute__((ext_vector_type(2)));
typedef f16 h4 __attribute__((ext_vector_type(4)));
typedef f16 h8 __attribute__((ext_vector_type(8)));

#define TT 512
#define HH 32
#define XPAD 516   // xbuf row stride (floats): rows 16B-aligned, <=2-way banks
#define HXPAD 36   // hx row stride (f16): 72B rows -> conflict-free b64
#define OPAD 68    // obuf row stride (floats)

#define LOG2E 1.44269504f

__device__ __forceinline__ float fast_sigm(float a) {   // sigmoid(a)
  return __builtin_amdgcn_rcpf(1.0f + __builtin_amdgcn_exp2f(-LOG2E * a));
}
__device__ __forceinline__ float fast_tanh(float a) {   // tanh(a)
  return __builtin_fmaf(-2.0f,
      __builtin_amdgcn_rcpf(1.0f + __builtin_amdgcn_exp2f(2.0f * LOG2E * a)),
      1.0f);
}
__device__ __forceinline__ h2 pack_h2(vf2 a, float s) {
  h2 r = {(f16)(a.x * s), (f16)(a.y * s)};
  return r;
}

// A-fragment for one 16x16x32 tile: row (ROW) of W_hh, this lane's 8 k's
// under the k = 4q+(e&3)+16*(e>>2) labeling, pre-scaled into exp2 domain.
#define LDA(P, ROW, S) \
  h8 P; { const vf2* rp = Wp + (size_t)(ROW) * 16; \
    const h2 a0 = pack_h2(rp[2*q],     (S)), a1 = pack_h2(rp[2*q+1],   (S)); \
    const h2 a2 = pack_h2(rp[8+2*q],   (S)), a3 = pack_h2(rp[8+2*q+1], (S)); \
    P = (h8){a0.x, a0.y, a1.x, a1.y, a2.x, a2.y, a3.x, a3.y}; }

__global__ __launch_bounds__(128)
__attribute__((amdgpu_waves_per_eu(1, 1)))
void gru_bidir_head(const float* __restrict__ X,
                    const float* __restrict__ Wih_f, const float* __restrict__ Whh_f,
                    const float* __restrict__ bih_f, const float* __restrict__ bhh_f,
                    const float* __restrict__ Wih_b,
                    const float* __restrict__ bih_b, const float* __restrict__ bhh_b,
                    const float* __restrict__ W1, const float* __restrict__ b1,
                    const float* __restrict__ W2, const float* __restrict__ b2,
                    float* __restrict__ out)
{
  __shared__ float xbuf[16][XPAD];       // staged input rows (33 KB)
  __shared__ f16   hx[2][16][HXPAD];     // h half-exchange, dbuf (2.3 KB)
  __shared__ float obuf[16][OPAD];       // [row][h_f(32) | h_b(32)] (4.3 KB)

  const int tid  = threadIdx.x;
  const int lane = tid & 63;
  const int Wv   = tid >> 6;             // wave: j in [16*Wv, 16*Wv+16)
  const int bq   = lane & 15;            // batch row within group (n-index)
  const int q    = lane >> 4;            // quad 0..3
  const int rb   = blockIdx.x << 4;      // global base row

  // --- stage 16 rows of X into LDS (coalesced: 128 thr x 1 vf4 per row) ---
  #pragma unroll 4
  for (int r = 0; r < 16; ++r)
    ((vf4*)&xbuf[r][0])[tid] = ((const vf4*)(X + (size_t)(rb + r) * TT))[tid];

  // --- A-fragments: W_hh rows (16W+bq | 32+.. | 64+..), exp2-scaled f16 ---
  const vf2* Wp = (const vf2*)Whh_f;     // row stride = 16 vf2
  const float s1 = -LOG2E;               // r,z: sigmoid domain (negated)
  const float s2 = 2.0f * LOG2E;         // n: tanh domain
  const int mrow = 16*Wv + bq;
  LDA(Ar, mrow,      s1);
  LDA(Az, 32 + mrow, s1);
  LDA(An, 64 + mrow, s2);

  // --- seed consts: C reg r corresponds to j = 16W + 4q + r ---
  const int j0 = 16*Wv + 4*q;
  vf4 xwr, cbr4, xwz, cbz4, xwn4, cbn4, Cn;
  #pragma unroll
  for (int r = 0; r < 4; ++r) {
    const int j = j0 + r;
    xwr[r]  = Wih_f[j] * s1;
    cbr4[r] = (bih_f[j] + bhh_f[j]) * s1;
    xwz[r]  = Wih_f[HH + j] * s1;
    cbz4[r] = (bih_f[HH + j] + bhh_f[HH + j]) * s1;
    xwn4[r] = Wih_f[2*HH + j] * s2;      // n: x-term (outside r*(.))
    cbn4[r] = bih_f[2*HH + j] * s2;      // n: b_ih term
    Cn[r]   = bhh_f[2*HH + j] * s2;      // n: b_hh term (inside r*(.)) = MFMA C
  }

  __syncthreads();                       // x staged (cross-wave)

  vf4 hold = {0.0f, 0.0f, 0.0f, 0.0f};   // h for (b=bq, j=j0+r), fp32
  h8  B = {};                             // h0 = 0
  const vf4* xrow = (const vf4*)&xbuf[bq][0];
  vf4 x4 = xrow[0];

  #pragma unroll 1
  for (int tg = 0; tg < TT / 4; ++tg) {
    const vf4 x4n = xrow[tg + 1 < TT / 4 ? tg + 1 : tg];   // off critical path

    #pragma unroll
    for (int u = 0; u < 4; ++u) {
      const float xb = (u == 0) ? x4.x : (u == 1) ? x4.y : (u == 2) ? x4.z : x4.w;

      // seeds ride the MFMA C operand (off the serial chain)
      const vf4 Cr = { __builtin_fmaf(xb, xwr.x, cbr4.x), __builtin_fmaf(xb, xwr.y, cbr4.y),
                       __builtin_fmaf(xb, xwr.z, cbr4.z), __builtin_fmaf(xb, xwr.w, cbr4.w) };
      const vf4 Cz = { __builtin_fmaf(xb, xwz.x, cbz4.x), __builtin_fmaf(xb, xwz.y, cbz4.y),
                       __builtin_fmaf(xb, xwz.z, cbz4.z), __builtin_fmaf(xb, xwz.w, cbz4.w) };
      const vf4 sn = { __builtin_fmaf(xb, xwn4.x, cbn4.x), __builtin_fmaf(xb, xwn4.y, cbn4.y),
                       __builtin_fmaf(xb, xwn4.z, cbn4.z), __builtin_fmaf(xb, xwn4.w, cbn4.w) };

      // gh = h @ W_hh.T (+seeds): one MFMA per gate-tile
      const vf4 Dr = __builtin_amdgcn_mfma_f32_16x16x32_f16(Ar, B, Cr, 0, 0, 0);
      const vf4 Dz = __builtin_amdgcn_mfma_f32_16x16x32_f16(Az, B, Cz, 0, 0, 0);
      const vf4 Dn = __builtin_amdgcn_mfma_f32_16x16x32_f16(An, B, Cn, 0, 0, 0);

      // epilogue: 4 j's per lane (D reg r -> j0+r, batch row bq)
      #pragma unroll
      for (int r = 0; r < 4; ++r) {
        const float rr = __builtin_amdgcn_rcpf(1.0f + __builtin_amdgcn_exp2f(Dr[r]));
        const float zz = __builtin_amdgcn_rcpf(1.0f + __builtin_amdgcn_exp2f(Dz[r]));
        const float y  = __builtin_fmaf(rr, Dn[r], sn[r]);
        const float nn = __builtin_fmaf(-2.0f,
            __builtin_amdgcn_rcpf(1.0f + __builtin_amdgcn_exp2f(y)), 1.0f);
        hold[r] = __builtin_fmaf(zz, hold[r] - nn, nn);   // (1-z)*n + z*h
      }

      // pack own half (f16, rne like R11) and exchange halves via LDS
      const h4 own = { (f16)hold.x, (f16)hold.y, (f16)hold.z, (f16)hold.w };
      *(h4*)&hx[u & 1][bq][16*Wv + 4*q] = own;            // ds_write_b64
      __syncthreads();                                    // dbuf -> 1 barrier/step
      const h4 lo = *(const h4*)&hx[u & 1][bq][4*q];      // k = 4q+(0..3)
      const h4 hi = *(const h4*)&hx[u & 1][bq][16 + 4*q]; // k = 16+4q+(0..3)
      B = (h8){lo[0], lo[1], lo[2], lo[3], hi[0], hi[1], hi[2], hi[3]};
    }
    x4 = x4n;
  }

  // --- publish h_f (fp32) ---
  *(vf4*)&obuf[bq][16*Wv + 4*q] = hold;
  __syncthreads();

  // --- backward (ONE GRU step from h0=0 on x[T-1]) + MLP head, per row ---
  const int g   = tid & 31;
  const int grp = tid >> 5;              // 4 groups of 32 lanes
  #pragma unroll 1
  for (int it = 0; it < 4; ++it) {
    const int row = grp + 4 * it;
    const float xl  = xbuf[row][TT - 1];
    const float rbv = fast_sigm(__builtin_fmaf(xl, Wih_b[g],      bih_b[g]      + bhh_b[g]));
    const float zbv = fast_sigm(__builtin_fmaf(xl, Wih_b[HH + g], bih_b[HH + g] + bhh_b[HH + g]));
    const float xnb = __builtin_fmaf(xl, Wih_b[2*HH + g], bih_b[2*HH + g]);
    const float nbv = fast_tanh(__builtin_fmaf(rbv, bhh_b[2*HH + g], xnb));
    const float hbv = nbv - zbv * nbv;   // (1-zb)*nb + zb*0
    obuf[row][32 + g] = hbv;
    __builtin_amdgcn_wave_barrier();

    const int jj = g & 15;               // lanes 16..31 duplicate
    const vf4* W1r = (const vf4*)(W1 + jj * 64);
    const vf4* hc  = (const vf4*)&obuf[row][0];
    vf4 a4 = W1r[0] * hc[0];
    #pragma unroll
    for (int qq = 1; qq < 16; ++qq)
      a4 = __builtin_elementwise_fma(W1r[qq], hc[qq], a4);
    float acc = b1[jj] + (a4.x + a4.y) + (a4.z + a4.w);
    float h1v = fmaxf(acc, 0.0f) * W2[jj];
    h1v += __shfl_down(h1v, 8, 16);
    h1v += __shfl_down(h1v, 4, 16);
    h1v += __shfl_down(h1v, 2, 16);
    h1v += __shfl_down(h1v, 1, 16);
    if (g == 0) out[rb + row] = fast_sigm(h1v + b2[0]);
  }
}

extern "C" void kernel_launch(void* const* d_in, const int* in_sizes, int n_in,
                              void* d_out, int out_size, void* d_ws, size_t ws_size,
                              hipStream_t stream) {
  const float* X     = (const float*)d_in[0];
  const float* Wih_f = (const float*)d_in[1];
  const float* Whh_f = (const float*)d_in[2];
  const float* bih_f = (const float*)d_in[3];
  const float* bhh_f = (const float*)d_in[4];
  const float* Wih_b = (const float*)d_in[5];
  // d_in[6] = W_hh_b: unused — backward direction runs exactly one step from h0=0.
  const float* bih_b = (const float*)d_in[7];
  const float* bhh_b = (const float*)d_in[8];
  const float* W1    = (const float*)d_in[9];
  const float* b1    = (const float*)d_in[10];
  const float* W2    = (const float*)d_in[11];
  const float* b2    = (const float*)d_in[12];
  float* out = (float*)d_out;

  // 2048 rows / 16 rows per block = 128 blocks x 128 thr (2 waves: gate-lo,
  // gate-hi). One block per CU; waves on separate SIMDs.
  gru_bidir_head<<<128, 128, 0, stream>>>(X, Wih_f, Whh_f, bih_f, bhh_f,
                                          Wih_b, bih_b, bhh_b, W1, b1, W2, b2, out);
}

// Round 6
// 177.902 us; speedup vs baseline: 1.3587x; 1.2354x over previous
//
#include <hip/hip_runtime.h>

// Bidirectional GRU (H=32, input=1, B=2048, T=512) + MLP head, fully fused.
//
// Reference takes out[:, -1, :] = concat(h_fwd after T steps, h_bwd after ONE
// step from h0=0 on x[T-1]) -> only the forward scan is sequential; W_hh_b is
// entirely unused.
//
// R17 = R11 (best measured: 112 us rocprof) with the 48 v_dot2_f32_f16
// replaced by 48 v_pk_fma_f32 (fp32 weights + fp32 h broadcast).
//
// Consolidated model (R8..R16):
//   * R11 wall 532 cyc/step = ~340 issue + ~190 stall at 1 wave/SIMD.
//   * R12 (DPP butterfly), R13/R14 (K-split), R15 (2 waves/SIMD on half the
//     CUs), R16 (MFMA recurrence) all lose: wave-geometry can't cut per-row
//     issue, and MFMA concentrates the epilogue (trans are quarter-rate ->
//     24-48 trans/step/wave dominates any concentrated design). Trans work
//     must stay distributed at ~1 element/lane: R11's shape is the shape.
//   * Remaining question: R11's issue fit requires fdot2 ~4 cyc (192 of 340).
//     If dot2 is half-rate, v_pk_fma_f32 (2 f32 MACs, full-rate) does the
//     same MACs in ~96 cyc. Costs: h broadcast f32 (8 ds_read_b128 vs 4,
//     +16), +6 combine adds, -1 cvt. Net S ~ 430-450 if H1, neutral if H0.
//   * Bonus: W_hh and h stay fp32 -> recurrence quantization gone, absmax
//     should drop ~10x.
//
// Structure (otherwise identical to R11):
//   * 32 lanes per row, full 32-wide dot per lane, no shfl; 2 rows per wave
//     as half-waves; 256 blocks x 256 thr = 1024 waves = 1 wave/SIMD.
//   * Weights fp32 vf2-packed (16 vf2 per gate = 96 VGPRs), pre-scaled into
//     exp2 domain (r/z by -log2e, n by 2log2e), pinned via inline-asm "+v".
//   * h state fp32; broadcast via ds_write_b32 + 8x broadcast ds_read_b128
//     (conflict-free; wave-internal in-order DS pipe, wave_barrier only).
//   * sigmoid = v_rcp(1+v_exp2(.)), tanh = 1-2*v_rcp(1+v_exp2(.)).
//   * x staged in LDS f32, consumed as vf4 per 4 steps (prefetched); x-term
//     FMAs for all 4 unrolled steps hoisted to the tg-loop top.

typedef float vf2 __attribute__((ext_vector_type(2)));
typedef float vf4 __attribute__((ext_vector_type(4)));
typedef _Float16 f16;

#define TT 512
#define HH 32

// inline-asm defs are not rematerializable: forces a real VGPR def here.
#define PIN(v) asm volatile("" : "+v"(v))

#define LOG2E 1.44269504f

__device__ __forceinline__ float fast_sigm(float a) {   // sigmoid(a)
  return __builtin_amdgcn_rcpf(1.0f + __builtin_amdgcn_exp2f(-LOG2E * a));
}
__device__ __forceinline__ float fast_tanh(float a) {   // tanh(a)
  return __builtin_fmaf(-2.0f,
      __builtin_amdgcn_rcpf(1.0f + __builtin_amdgcn_exp2f(2.0f * LOG2E * a)),
      1.0f);
}

// load one 32-float W_hh row as 16 fp32 vf2 regs, pre-scaled, pinned
#define LDW16(P, BASE, S) \
  vf2 P##0=Wp[(BASE)+0]*(S),  P##1=Wp[(BASE)+1]*(S), \
      P##2=Wp[(BASE)+2]*(S),  P##3=Wp[(BASE)+3]*(S), \
      P##4=Wp[(BASE)+4]*(S),  P##5=Wp[(BASE)+5]*(S), \
      P##6=Wp[(BASE)+6]*(S),  P##7=Wp[(BASE)+7]*(S), \
      P##8=Wp[(BASE)+8]*(S),  P##9=Wp[(BASE)+9]*(S), \
      P##A=Wp[(BASE)+10]*(S), P##B=Wp[(BASE)+11]*(S), \
      P##C=Wp[(BASE)+12]*(S), P##D=Wp[(BASE)+13]*(S), \
      P##E=Wp[(BASE)+14]*(S), P##F=Wp[(BASE)+15]*(S); \
  PIN(P##0);PIN(P##1);PIN(P##2);PIN(P##3);PIN(P##4);PIN(P##5);PIN(P##6);PIN(P##7); \
  PIN(P##8);PIN(P##9);PIN(P##A);PIN(P##B);PIN(P##C);PIN(P##D);PIN(P##E);PIN(P##F)

// 16 v_pk_fma_f32 of (q0..qF).(P0..PF) into two vf2 chains; OUT = total + SEED.
#define FPK16(OUT, P, SEED) \
  float OUT; { \
    vf2 c0 = {(SEED), 0.0f}, c1 = {0.0f, 0.0f}; \
    c0 = __builtin_elementwise_fma(q0, P##0, c0);  c1 = __builtin_elementwise_fma(q1, P##1, c1); \
    c0 = __builtin_elementwise_fma(q2, P##2, c0);  c1 = __builtin_elementwise_fma(q3, P##3, c1); \
    c0 = __builtin_elementwise_fma(q4, P##4, c0);  c1 = __builtin_elementwise_fma(q5, P##5, c1); \
    c0 = __builtin_elementwise_fma(q6, P##6, c0);  c1 = __builtin_elementwise_fma(q7, P##7, c1); \
    c0 = __builtin_elementwise_fma(q8, P##8, c0);  c1 = __builtin_elementwise_fma(q9, P##9, c1); \
    c0 = __builtin_elementwise_fma(qA, P##A, c0);  c1 = __builtin_elementwise_fma(qB, P##B, c1); \
    c0 = __builtin_elementwise_fma(qC, P##C, c0);  c1 = __builtin_elementwise_fma(qD, P##D, c1); \
    c0 = __builtin_elementwise_fma(qE, P##E, c0);  c1 = __builtin_elementwise_fma(qF, P##F, c1); \
    OUT = (c0.x + c1.x) + (c0.y + c1.y); }

__global__ __launch_bounds__(256)
__attribute__((amdgpu_waves_per_eu(1, 1)))
void gru_bidir_head(const float* __restrict__ X,
                    const float* __restrict__ Wih_f, const float* __restrict__ Whh_f,
                    const float* __restrict__ bih_f, const float* __restrict__ bhh_f,
                    const float* __restrict__ Wih_b,
                    const float* __restrict__ bih_b, const float* __restrict__ bhh_b,
                    const float* __restrict__ W1, const float* __restrict__ b1,
                    const float* __restrict__ W2, const float* __restrict__ b2,
                    float* __restrict__ out)
{
  __shared__ float xbuf[8][TT];        // staged input rows (16 KB)
  __shared__ float hbuf[8][HH];        // h broadcast, fp32 (1 KB)
  __shared__ float obuf[8][64];        // [row][h_f(32) | h_b(32)] (2 KB)

  const int g  = threadIdx.x & 31;     // lane within row group = output index i
  const int rs = threadIdx.x >> 5;     // row slot in block (0..7)
  const int b  = (blockIdx.x << 3) + rs;

  // --- stage this row of X into LDS (4 x vf4 per lane, coalesced) ---
  const vf4* Xr4 = (const vf4*)(X + (size_t)b * TT);
  vf4* xb4 = (vf4*)&xbuf[rs][0];
  #pragma unroll
  for (int q = 0; q < 4; ++q) xb4[g + 32 * q] = Xr4[g + 32 * q];

  // --- per-lane weights: W_hh rows g (r), 32+g (z), 64+g (n); pre-scaled
  //     into exp2 domain, fp32 vf2-packed, pinned (96 VGPRs) ---
  const vf2* Wp = (const vf2*)Whh_f;   // row stride = 16 vf2
  const float s1 = -LOG2E;             // r,z: sigmoid domain (negated)
  const float s2 = 2.0f * LOG2E;       // n: tanh domain
  LDW16(Wr, (g)        * 16, s1);
  LDW16(Wz, (HH + g)   * 16, s1);
  LDW16(Wn, (2*HH + g) * 16, s2);

  float xwr = Wih_f[g] * s1, xwz = Wih_f[HH + g] * s1, xwn = Wih_f[2*HH + g] * s2;
  float cbr = (bih_f[g]      + bhh_f[g])      * s1;
  float cbz = (bih_f[HH + g] + bhh_f[HH + g]) * s1;
  float cbn = bih_f[2*HH + g] * s2;            // n: b_ih term (with x)
  float cbh = bhh_f[2*HH + g] * s2;            // n: b_hh term (inside r*(...))
  PIN(xwr); PIN(xwz); PIN(xwn); PIN(cbr); PIN(cbz); PIN(cbn); PIN(cbh);

  float h = 0.0f;
  hbuf[rs][g] = 0.0f;
  __builtin_amdgcn_wave_barrier();

  const vf4* hv = (const vf4*)&hbuf[rs][0];    // 8 x b128 = all 32 fp32 h
  const vf4* xv = (const vf4*)&xbuf[rs][0];
  vf4 x4 = xv[0];

  #pragma unroll 1
  for (int tg = 0; tg < TT / 4; ++tg) {
    const vf4 x4n = xv[tg + 1 < TT / 4 ? tg + 1 : tg];   // off critical path

    // hoist ALL x-dependent terms for the 4 sub-steps: issued during the
    // first read stall, off the per-step serial chain.
    float sr0 = __builtin_fmaf(x4.x, xwr, cbr), sz0 = __builtin_fmaf(x4.x, xwz, cbz),
          sn0 = __builtin_fmaf(x4.x, xwn, cbn);
    float sr1 = __builtin_fmaf(x4.y, xwr, cbr), sz1 = __builtin_fmaf(x4.y, xwz, cbz),
          sn1 = __builtin_fmaf(x4.y, xwn, cbn);
    float sr2 = __builtin_fmaf(x4.z, xwr, cbr), sz2 = __builtin_fmaf(x4.z, xwz, cbz),
          sn2 = __builtin_fmaf(x4.z, xwn, cbn);
    float sr3 = __builtin_fmaf(x4.w, xwr, cbr), sz3 = __builtin_fmaf(x4.w, xwz, cbz),
          sn3 = __builtin_fmaf(x4.w, xwn, cbn);

    #pragma unroll
    for (int u = 0; u < 4; ++u) {
      const float sr = (u == 0) ? sr0 : (u == 1) ? sr1 : (u == 2) ? sr2 : sr3;
      const float sz = (u == 0) ? sz0 : (u == 1) ? sz1 : (u == 2) ? sz2 : sz3;
      const float sn = (u == 0) ? sn0 : (u == 1) ? sn1 : (u == 2) ? sn2 : sn3;

      // all 32 h (fp32): 8 broadcast ds_read_b128 (conflict-free; compiler
      // pipelines lgkmcnt so dots on H0 start before H7 lands)
      const vf4 H0 = hv[0], H1 = hv[1], H2 = hv[2], H3 = hv[3],
                H4 = hv[4], H5 = hv[5], H6 = hv[6], H7 = hv[7];
      const vf2 q0 = {H0.x, H0.y}, q1 = {H0.z, H0.w},
                q2 = {H1.x, H1.y}, q3 = {H1.z, H1.w},
                q4 = {H2.x, H2.y}, q5 = {H2.z, H2.w},
                q6 = {H3.x, H3.y}, q7 = {H3.z, H3.w},
                q8 = {H4.x, H4.y}, q9 = {H4.z, H4.w},
                qA = {H5.x, H5.y}, qB = {H5.z, H5.w},
                qC = {H6.x, H6.y}, qD = {H6.z, H6.w},
                qE = {H7.x, H7.y}, qF = {H7.z, H7.w};

      FPK16(ar, Wr, sr);                // includes x-term + bias
      FPK16(az, Wz, sz);
      FPK16(an, Wn, cbh);               // n: b_hh seed (inside r*(.))

      const float r = __builtin_amdgcn_rcpf(1.0f + __builtin_amdgcn_exp2f(ar));
      const float z = __builtin_amdgcn_rcpf(1.0f + __builtin_amdgcn_exp2f(az));
      const float y = __builtin_fmaf(r, an, sn);
      const float n = __builtin_fmaf(-2.0f,
          __builtin_amdgcn_rcpf(1.0f + __builtin_amdgcn_exp2f(y)), 1.0f);
      h = __builtin_fmaf(z, h - n, n);           // (1-z)*n + z*h

      hbuf[rs][g] = h;                           // ds_write_b32 (fp32, no cvt)
      __builtin_amdgcn_wave_barrier();           // wave-synchronous ordering
    }
    x4 = x4n;
  }

  // --- backward direction: exactly ONE GRU step from h0=0 on x[T-1] ---
  const float xl  = xbuf[rs][TT - 1];
  const float rb  = fast_sigm(__builtin_fmaf(xl, Wih_b[g],      bih_b[g]      + bhh_b[g]));
  const float zb  = fast_sigm(__builtin_fmaf(xl, Wih_b[HH + g], bih_b[HH + g] + bhh_b[HH + g]));
  const float xnb = __builtin_fmaf(xl, Wih_b[2*HH + g], bih_b[2*HH + g]);
  const float nb  = fast_tanh(__builtin_fmaf(rb, bhh_b[2*HH + g], xnb));
  const float hb  = nb - zb * nb;                // (1-zb)*nb + zb*0

  obuf[rs][g]      = h;                          // h_f (full fp32 state)
  obuf[rs][32 + g] = hb;                         // h_b
  __builtin_amdgcn_wave_barrier();

  // --- MLP head: sigmoid(W2 @ relu(W1 @ [h_f,h_b] + b1) + b2) ---
  const int j = g & 15;                          // lanes 16..31 duplicate
  const vf4* W1r = (const vf4*)(W1 + j * 64);
  const vf4* hc  = (const vf4*)&obuf[rs][0];
  vf4 a4 = W1r[0] * hc[0];
  #pragma unroll
  for (int q = 1; q < 16; ++q)
    a4 = __builtin_elementwise_fma(W1r[q], hc[q], a4);
  float acc = b1[j] + (a4.x + a4.y) + (a4.z + a4.w);
  float h1 = fmaxf(acc, 0.0f) * W2[j];
  h1 += __shfl_down(h1, 8, 16);
  h1 += __shfl_down(h1, 4, 16);
  h1 += __shfl_down(h1, 2, 16);
  h1 += __shfl_down(h1, 1, 16);
  if (g == 0) out[b] = fast_sigm(h1 + b2[0]);
}

extern "C" void kernel_launch(void* const* d_in, const int* in_sizes, int n_in,
                              void* d_out, int out_size, void* d_ws, size_t ws_size,
                              hipStream_t stream) {
  const float* X     = (const float*)d_in[0];
  const float* Wih_f = (const float*)d_in[1];
  const float* Whh_f = (const float*)d_in[2];
  const float* bih_f = (const float*)d_in[3];
  const float* bhh_f = (const float*)d_in[4];
  const float* Wih_b = (const float*)d_in[5];
  // d_in[6] = W_hh_b: unused — backward direction runs exactly one step from h0=0.
  const float* bih_b = (const float*)d_in[7];
  const float* bhh_b = (const float*)d_in[8];
  const float* W1    = (const float*)d_in[9];
  const float* b1    = (const float*)d_in[10];
  const float* W2    = (const float*)d_in[11];
  const float* b2    = (const float*)d_in[12];
  float* out = (float*)d_out;

  // 2048 rows / 8 rows per 256-thread block = 256 blocks = 1 block/CU,
  // 1024 waves = 1 wave/SIMD (2 rows per wave as half-waves).
  gru_bidir_head<<<256, 256, 0, stream>>>(X, Wih_f, Whh_f, bih_f, bhh_f,
                                          Wih_b, bih_b, bhh_b, W1, b1, W2, b2, out);
}